// Round 1
// baseline (774.623 us; speedup 1.0000x reference)
//
#include <hip/hip_runtime.h>
#include <math.h>

#define SIGMA 0.05f

// ---------------------------------------------------------------------------
// fc_tanh: out[b,j] = tanh(in[b,:] @ W[:,j] + bias[j]),  in:[1024,256] W:[256,256]
// one block per row b, 256 threads (one per output j). W read coalesced row-wise.
// Also zeroes the argmax accumulator (stream-ordered before the argmax kernel).
// ---------------------------------------------------------------------------
__global__ __launch_bounds__(256) void fc_tanh_kernel(
    const float* __restrict__ in, const float* __restrict__ W,
    const float* __restrict__ bias, float* __restrict__ out,
    int* acc_zero)
{
    __shared__ float s[256];
    const int b = blockIdx.x, j = threadIdx.x;
    s[j] = in[b * 256 + j];
    __syncthreads();
    float acc = bias[j];
#pragma unroll 8
    for (int k = 0; k < 256; ++k)
        acc = fmaf(s[k], W[k * 256 + j], acc);
    out[b * 256 + j] = tanhf(acc);
    if (acc_zero != nullptr && b == 0 && j == 0) *acc_zero = 0;
}

// ---------------------------------------------------------------------------
// fc3: logits[b,d] = h2[b,:] @ W3[:,d] + b3[d],  h2:[1024,256] W3:[256,1024]
// block = 256 threads computes an 8-row x 256-col tile. grid = (4, 128).
// 8-row blocking cuts W3 re-reads to 128 MiB total (L2-served).
// ---------------------------------------------------------------------------
__global__ __launch_bounds__(256) void fc3_kernel(
    const float* __restrict__ h2, const float* __restrict__ W3,
    const float* __restrict__ b3, float* __restrict__ logits)
{
    __shared__ float s[8 * 256];
    const int tid = threadIdx.x;
    const int col = blockIdx.x * 256 + tid;
    const int row0 = blockIdx.y * 8;
#pragma unroll
    for (int r = 0; r < 8; ++r)
        s[r * 256 + tid] = h2[(row0 + r) * 256 + tid];
    __syncthreads();
    float acc[8];
    const float bb = b3[col];
#pragma unroll
    for (int r = 0; r < 8; ++r) acc[r] = bb;
    for (int k = 0; k < 256; ++k) {
        const float w = W3[(size_t)k * 1024 + col];
#pragma unroll
        for (int r = 0; r < 8; ++r)
            acc[r] = fmaf(s[r * 256 + k], w, acc[r]);  // LDS read is broadcast
    }
#pragma unroll
    for (int r = 0; r < 8; ++r)
        logits[(size_t)(row0 + r) * 1024 + col] = acc[r];
}

// ---------------------------------------------------------------------------
// softmax in-place over rows of [1024,1024]. One block per row, 4 elems/thread.
// ---------------------------------------------------------------------------
__global__ __launch_bounds__(256) void softmax_kernel(float* __restrict__ logits)
{
    __shared__ float red[4];
    const int b = blockIdx.x, tid = threadIdx.x;
    const int lane = tid & 63, wave = tid >> 6;
    float* row = logits + (size_t)b * 1024;
    float4 v = *(const float4*)(row + tid * 4);

    float m = fmaxf(fmaxf(v.x, v.y), fmaxf(v.z, v.w));
#pragma unroll
    for (int off = 1; off < 64; off <<= 1) m = fmaxf(m, __shfl_xor(m, off));
    if (lane == 0) red[wave] = m;
    __syncthreads();
    const float M = fmaxf(fmaxf(red[0], red[1]), fmaxf(red[2], red[3]));

    float4 e;
    e.x = expf(v.x - M); e.y = expf(v.y - M);
    e.z = expf(v.z - M); e.w = expf(v.w - M);
    float ssum = e.x + e.y + e.z + e.w;
#pragma unroll
    for (int off = 1; off < 64; off <<= 1) ssum += __shfl_xor(ssum, off);
    __syncthreads();               // red reuse
    if (lane == 0) red[wave] = ssum;
    __syncthreads();
    const float inv = 1.0f / (red[0] + red[1] + red[2] + red[3]);
    e.x *= inv; e.y *= inv; e.z *= inv; e.w *= inv;
    *(float4*)(row + tid * 4) = e;
}

// ---------------------------------------------------------------------------
// argmax scan: for each (b,n) find argmax_d(probs[b,d] + SIGMA*noise[b,n,d]),
// accumulate exact integer sum of indices. grid = B*4 blocks, each block does
// 32 n-values for one b (one n per wave per iteration). Noise read = 512 MiB,
// fully coalesced float4 — this kernel is the HBM-bound floor of the problem.
// ---------------------------------------------------------------------------
#define NSPLIT 4
__global__ __launch_bounds__(256) void argmax_kernel(
    const float* __restrict__ probs, const float* __restrict__ noise,
    int* __restrict__ acc)
{
    __shared__ float ps[1024];
    __shared__ int wsum[4];
    const int b = blockIdx.x / NSPLIT;
    const int part = blockIdx.x % NSPLIT;
    const int tid = threadIdx.x;
    const int lane = tid & 63, wave = tid >> 6;

    for (int i = tid; i < 1024; i += 256)
        ps[i] = probs[(size_t)b * 1024 + i];
    __syncthreads();

    const int nper = 128 / NSPLIT;  // 32
    int mysum = 0;
    for (int ni = wave; ni < nper; ni += 4) {
        const int n = part * nper + ni;
        const float* __restrict__ np_ = noise + ((size_t)b * 128 + n) * 1024;

        // lane covers float4 chunks lane, lane+64, lane+128, lane+192
        const float4 n0 = *(const float4*)(np_ + (size_t)(lane        ) * 4);
        const float4 n1 = *(const float4*)(np_ + (size_t)(lane +  64) * 4);
        const float4 n2 = *(const float4*)(np_ + (size_t)(lane + 128) * 4);
        const float4 n3 = *(const float4*)(np_ + (size_t)(lane + 192) * 4);
        const float4 p0 = *(const float4*)(ps + (lane        ) * 4);
        const float4 p1 = *(const float4*)(ps + (lane +  64) * 4);
        const float4 p2 = *(const float4*)(ps + (lane + 128) * 4);
        const float4 p3 = *(const float4*)(ps + (lane + 192) * 4);

        float best = -1e30f; int bidx = 0;
        // strict > keeps the lowest d on ties (in-lane d is visited ascending)
#define CHK(val, d) { float _v = (val); if (_v > best) { best = _v; bidx = (d); } }
        int d0 = lane * 4;
        CHK(fmaf(n0.x, SIGMA, p0.x), d0 + 0); CHK(fmaf(n0.y, SIGMA, p0.y), d0 + 1);
        CHK(fmaf(n0.z, SIGMA, p0.z), d0 + 2); CHK(fmaf(n0.w, SIGMA, p0.w), d0 + 3);
        d0 = (lane + 64) * 4;
        CHK(fmaf(n1.x, SIGMA, p1.x), d0 + 0); CHK(fmaf(n1.y, SIGMA, p1.y), d0 + 1);
        CHK(fmaf(n1.z, SIGMA, p1.z), d0 + 2); CHK(fmaf(n1.w, SIGMA, p1.w), d0 + 3);
        d0 = (lane + 128) * 4;
        CHK(fmaf(n2.x, SIGMA, p2.x), d0 + 0); CHK(fmaf(n2.y, SIGMA, p2.y), d0 + 1);
        CHK(fmaf(n2.z, SIGMA, p2.z), d0 + 2); CHK(fmaf(n2.w, SIGMA, p2.w), d0 + 3);
        d0 = (lane + 192) * 4;
        CHK(fmaf(n3.x, SIGMA, p3.x), d0 + 0); CHK(fmaf(n3.y, SIGMA, p3.y), d0 + 1);
        CHK(fmaf(n3.z, SIGMA, p3.z), d0 + 2); CHK(fmaf(n3.w, SIGMA, p3.w), d0 + 3);
#undef CHK

        // 64-lane butterfly: max value, ties -> lowest index
#pragma unroll
        for (int off = 1; off < 64; off <<= 1) {
            const float ov = __shfl_xor(best, off);
            const int   oi = __shfl_xor(bidx, off);
            if (ov > best || (ov == best && oi < bidx)) { best = ov; bidx = oi; }
        }
        mysum += bidx;
    }
    if (lane == 0) wsum[wave] = mysum;
    __syncthreads();
    if (tid == 0)
        atomicAdd(acc, wsum[0] + wsum[1] + wsum[2] + wsum[3]);
}

// ---------------------------------------------------------------------------
// value head: Q[b] = tanh([obs[b,:], c] @ Wv1 + bv1) @ Wv2 + bv2,
// c = (float)acc / 128. One block per b, thread j computes hidden unit j.
// ---------------------------------------------------------------------------
__global__ __launch_bounds__(256) void value_kernel(
    const float* __restrict__ obs, const float* __restrict__ Wv1,
    const float* __restrict__ bv1, const float* __restrict__ Wv2,
    const float* __restrict__ bv2, const int* __restrict__ acc,
    float* __restrict__ Q)
{
    __shared__ float s[256];
    __shared__ float red[4];
    const int b = blockIdx.x, j = threadIdx.x;
    const int lane = j & 63, wave = j >> 6;
    s[j] = obs[b * 256 + j];
    __syncthreads();
    const float c = (float)(*acc) * (1.0f / 128.0f);
    float a = bv1[j] + c * Wv1[256 * 256 + j];   // last row of Wv1 (k = OBS)
#pragma unroll 8
    for (int k = 0; k < 256; ++k)
        a = fmaf(s[k], Wv1[k * 256 + j], a);
    float v = tanhf(a) * Wv2[j];
#pragma unroll
    for (int off = 1; off < 64; off <<= 1) v += __shfl_xor(v, off);
    if (lane == 0) red[wave] = v;
    __syncthreads();
    if (j == 0) Q[b] = red[0] + red[1] + red[2] + red[3] + bv2[0];
}

// ---------------------------------------------------------------------------
extern "C" void kernel_launch(void* const* d_in, const int* in_sizes, int n_in,
                              void* d_out, int out_size, void* d_ws, size_t ws_size,
                              hipStream_t stream)
{
    const float* obs   = (const float*)d_in[0];
    const float* noise = (const float*)d_in[1];
    const float* W1    = (const float*)d_in[2];
    const float* b1    = (const float*)d_in[3];
    const float* W2    = (const float*)d_in[4];
    const float* b2    = (const float*)d_in[5];
    const float* W3    = (const float*)d_in[6];
    const float* b3    = (const float*)d_in[7];
    const float* Wv1   = (const float*)d_in[8];
    const float* bv1   = (const float*)d_in[9];
    const float* Wv2   = (const float*)d_in[10];
    const float* bv2   = (const float*)d_in[11];
    float* Q = (float*)d_out;

    // workspace layout (floats): h1[256K] h2[256K] logits/probs[1M] acc[1 int]
    float* ws     = (float*)d_ws;
    float* h1     = ws;
    float* h2     = h1 + 1024 * 256;
    float* logits = h2 + 1024 * 256;
    int*   acc    = (int*)(logits + 1024 * 1024);

    fc_tanh_kernel<<<1024, 256, 0, stream>>>(obs, W1, b1, h1, acc);
    fc_tanh_kernel<<<1024, 256, 0, stream>>>(h1, W2, b2, h2, nullptr);
    fc3_kernel<<<dim3(4, 128), 256, 0, stream>>>(h2, W3, b3, logits);
    softmax_kernel<<<1024, 256, 0, stream>>>(logits);
    argmax_kernel<<<1024 * NSPLIT, 256, 0, stream>>>(logits, noise, acc);
    value_kernel<<<1024, 256, 0, stream>>>(obs, Wv1, bv1, Wv2, bv2, acc, Q);
}